// Round 1
// baseline (701.647 us; speedup 1.0000x reference)
//
#include <hip/hip_runtime.h>
#include <math.h>

// GCN 2-layer: N=100000 nodes, E=3200000 edges, 128 -> 16 -> 7
constexpr int NN = 100000;
constexpr int NE = 3200000;
constexpr int DF = 128;
constexpr int NH = 16;
constexpr int NC = 7;

// ---------------- degree / dinv ----------------
__global__ void k_init_deg(float* __restrict__ deg) {
    int n = blockIdx.x * blockDim.x + threadIdx.x;
    if (n < NN) deg[n] = 1.0f;  // self-loop weight
}

__global__ void k_deg_scatter(const int* __restrict__ dst,
                              const float* __restrict__ w,
                              float* __restrict__ deg) {
    int e = blockIdx.x * blockDim.x + threadIdx.x;
    if (e < NE) atomicAdd(&deg[dst[e]], w[e]);
}

__global__ void k_deg_finalize(float* __restrict__ deg) {
    int n = blockIdx.x * blockDim.x + threadIdx.x;
    if (n < NN) deg[n] = rsqrtf(deg[n]);  // deg >= 1 always (self-loop)
}

// ---------------- layer 1 projection: h1 = x @ W1 ----------------
// thread t -> (node n = t/16, feature f = t%16); W1 staged in LDS.
__global__ void k_proj1(const float* __restrict__ x,
                        const float* __restrict__ W1,
                        float* __restrict__ h1) {
    __shared__ float Ws[DF * NH];
    for (int i = threadIdx.x; i < DF * NH; i += blockDim.x) Ws[i] = W1[i];
    __syncthreads();
    int t = blockIdx.x * blockDim.x + threadIdx.x;
    if (t >= NN * NH) return;
    int n = t >> 4;
    int f = t & 15;
    const float4* xr = (const float4*)(x + (size_t)n * DF);
    float acc = 0.0f;
#pragma unroll
    for (int k4 = 0; k4 < DF / 4; ++k4) {
        float4 xv = xr[k4];
        acc += xv.x * Ws[(k4 * 4 + 0) * NH + f];
        acc += xv.y * Ws[(k4 * 4 + 1) * NH + f];
        acc += xv.z * Ws[(k4 * 4 + 2) * NH + f];
        acc += xv.w * Ws[(k4 * 4 + 3) * NH + f];
    }
    h1[t] = acc;
}

// ---------------- aggregation init (self-loop term) ----------------
// out[n,f] = h[n,f] * dinv[n]^2
__global__ void k_agg_init(const float* __restrict__ h,
                           const float* __restrict__ dinv,
                           float* __restrict__ out,
                           int n_feat, int total) {
    int t = blockIdx.x * blockDim.x + threadIdx.x;
    if (t >= total) return;
    int n = t / n_feat;
    float d = dinv[n];
    out[t] = h[t] * d * d;
}

// ---------------- layer 1 edge scatter (16 feats) ----------------
__global__ void k_agg1_edges(const int* __restrict__ src,
                             const int* __restrict__ dst,
                             const float* __restrict__ w,
                             const float* __restrict__ dinv,
                             const float* __restrict__ h1,
                             float* __restrict__ out1) {
    int t = blockIdx.x * blockDim.x + threadIdx.x;
    if (t >= NE * NH) return;
    int e = t >> 4;
    int f = t & 15;
    int s = src[e];
    int d = dst[e];
    float norm = dinv[s] * w[e] * dinv[d];
    atomicAdd(&out1[d * NH + f], h1[s * NH + f] * norm);
}

// ---------------- relu(out1+b1) @ W2 -> h2 ----------------
__global__ void k_relu_proj2(const float* __restrict__ out1,
                             const float* __restrict__ b1,
                             const float* __restrict__ W2,
                             float* __restrict__ h2) {
    int n = blockIdx.x * blockDim.x + threadIdx.x;
    if (n >= NN) return;
    float hr[NH];
#pragma unroll
    for (int k = 0; k < NH; ++k)
        hr[k] = fmaxf(out1[n * NH + k] + b1[k], 0.0f);
#pragma unroll
    for (int c = 0; c < NC; ++c) {
        float acc = 0.0f;
#pragma unroll
        for (int k = 0; k < NH; ++k) acc += hr[k] * W2[k * NC + c];
        h2[n * NC + c] = acc;
    }
}

// ---------------- layer 2 edge scatter (7 feats, 8 thr/edge) ----------------
__global__ void k_agg2_edges(const int* __restrict__ src,
                             const int* __restrict__ dst,
                             const float* __restrict__ w,
                             const float* __restrict__ dinv,
                             const float* __restrict__ h2,
                             float* __restrict__ out2) {
    int t = blockIdx.x * blockDim.x + threadIdx.x;
    if (t >= NE * 8) return;
    int e = t >> 3;
    int c = t & 7;
    if (c >= NC) return;
    int s = src[e];
    int d = dst[e];
    float norm = dinv[s] * w[e] * dinv[d];
    atomicAdd(&out2[d * NC + c], h2[s * NC + c] * norm);
}

// ---------------- +b2, log_softmax ----------------
__global__ void k_logsoftmax(const float* __restrict__ out2,
                             const float* __restrict__ b2,
                             float* __restrict__ out) {
    int n = blockIdx.x * blockDim.x + threadIdx.x;
    if (n >= NN) return;
    float v[NC];
    float m = -1e30f;
#pragma unroll
    for (int c = 0; c < NC; ++c) {
        v[c] = out2[n * NC + c] + b2[c];
        m = fmaxf(m, v[c]);
    }
    float s = 0.0f;
#pragma unroll
    for (int c = 0; c < NC; ++c) s += expf(v[c] - m);
    float lse = m + logf(s);
#pragma unroll
    for (int c = 0; c < NC; ++c) out[n * NC + c] = v[c] - lse;
}

extern "C" void kernel_launch(void* const* d_in, const int* in_sizes, int n_in,
                              void* d_out, int out_size, void* d_ws, size_t ws_size,
                              hipStream_t stream) {
    const float* x  = (const float*)d_in[0];
    const int*   ei = (const int*)d_in[1];    // [2, NE] int32 (JAX x64 disabled)
    const float* ew = (const float*)d_in[2];
    const float* W1 = (const float*)d_in[3];
    const float* b1 = (const float*)d_in[4];
    const float* W2 = (const float*)d_in[5];
    const float* b2 = (const float*)d_in[6];
    float* out = (float*)d_out;

    const int* srcp = ei;
    const int* dstp = ei + NE;

    // workspace layout (floats), d_ws is poisoned 0xAA each call -> init everything
    float* ws   = (float*)d_ws;
    float* dinv = ws;                       // NN
    float* h1   = dinv + 100352;            // NN*NH  (offset padded to 256B)
    float* out1 = h1 + (size_t)NN * NH;     // NN*NH
    float* h2   = out1 + (size_t)NN * NH;   // NN*NC
    float* out2 = h2 + (size_t)NN * NC;     // NN*NC

    const int B = 256;
    auto cdiv = [](long long a, long long b) { return (int)((a + b - 1) / b); };

    k_init_deg<<<cdiv(NN, B), B, 0, stream>>>(dinv);
    k_deg_scatter<<<cdiv(NE, B), B, 0, stream>>>(dstp, ew, dinv);
    k_deg_finalize<<<cdiv(NN, B), B, 0, stream>>>(dinv);

    k_proj1<<<cdiv((long long)NN * NH, B), B, 0, stream>>>(x, W1, h1);

    k_agg_init<<<cdiv((long long)NN * NH, B), B, 0, stream>>>(h1, dinv, out1, NH, NN * NH);
    k_agg1_edges<<<cdiv((long long)NE * NH, B), B, 0, stream>>>(srcp, dstp, ew, dinv, h1, out1);

    k_relu_proj2<<<cdiv(NN, B), B, 0, stream>>>(out1, b1, W2, h2);

    k_agg_init<<<cdiv((long long)NN * NC, B), B, 0, stream>>>(h2, dinv, out2, NC, NN * NC);
    k_agg2_edges<<<cdiv((long long)NE * 8, B), B, 0, stream>>>(srcp, dstp, ew, dinv, h2, out2);

    k_logsoftmax<<<cdiv(NN, B), B, 0, stream>>>(out2, b2, out);
}